// Round 1
// baseline (438.760 us; speedup 1.0000x reference)
//
#include <hip/hip_runtime.h>

#define NODES 50000
#define EDGES 800000
#define FDIM  96
#define NCLS  40

// ---------------- CSR build ----------------

__global__ void zero_int_kernel(int* __restrict__ p, int n) {
  int i = blockIdx.x * blockDim.x + threadIdx.x;
  if (i < n) p[i] = 0;
}

__global__ void count_deg_kernel(const int* __restrict__ dst, int* __restrict__ cnt) {
  int e = blockIdx.x * blockDim.x + threadIdx.x;
  if (e < EDGES) atomicAdd(&cnt[dst[e]], 1);
}

__global__ __launch_bounds__(1024) void scan_kernel(const int* __restrict__ cnt,
                                                    int* __restrict__ row_ptr,
                                                    int* __restrict__ cursor) {
  __shared__ int part[1024];
  const int CH = (NODES + 1023) / 1024;  // 49
  int t = threadIdx.x;
  int base = t * CH;
  int s = 0;
  for (int i = 0; i < CH; ++i) {
    int idx = base + i;
    if (idx < NODES) s += cnt[idx];
  }
  part[t] = s;
  __syncthreads();
  for (int d = 1; d < 1024; d <<= 1) {
    int v = (t >= d) ? part[t - d] : 0;
    __syncthreads();
    part[t] += v;
    __syncthreads();
  }
  int run = part[t] - s;  // exclusive prefix of this thread's chunk
  for (int i = 0; i < CH; ++i) {
    int idx = base + i;
    if (idx < NODES) {
      row_ptr[idx] = run;
      cursor[idx]  = run;
      run += cnt[idx];
    }
  }
  if (t == 1023) row_ptr[NODES] = part[1023];
}

__global__ void fill_csr_kernel(const int* __restrict__ src, const int* __restrict__ dst,
                                int* __restrict__ cursor, int* __restrict__ col) {
  int e = blockIdx.x * blockDim.x + threadIdx.x;
  if (e < EDGES) {
    int d = dst[e];
    int pos = atomicAdd(&cursor[d], 1);
    col[pos] = src[e];
  }
}

// ---------------- aggregation: z[i] = h[i] + sum_{j->i} h[j] ----------------
// 32 lanes per node, 3 features per lane (96 = 32*3), register accumulation.

__global__ __launch_bounds__(256) void aggregate_kernel(const float* __restrict__ hin,
    const int* __restrict__ row_ptr, const int* __restrict__ col, float* __restrict__ z) {
  int gt = blockIdx.x * blockDim.x + threadIdx.x;
  int node = gt >> 5;
  int l = gt & 31;
  if (node >= NODES) return;
  const float* self = hin + (size_t)node * FDIM;
  float a0 = self[l], a1 = self[l + 32], a2 = self[l + 64];
  int e1 = row_ptr[node + 1];
  for (int e = row_ptr[node]; e < e1; ++e) {
    const float* r = hin + (size_t)col[e] * FDIM;
    a0 += r[l];
    a1 += r[l + 32];
    a2 += r[l + 64];
  }
  float* zp = z + (size_t)node * FDIM;
  zp[l] = a0; zp[l + 32] = a1; zp[l + 64] = a2;
}

// ---------------- tiled f32 GEMM: out[n, j] = relu?(in[n,:] @ W[:, j] + b[j]) ----------------
// Block tile: 64 nodes x NOUT. 192 threads = 16 node-threads (TM=4) x 12 out-threads (TN=NPAD/12).
// z-tile staged transposed in LDS with XOR quad-swizzle (avoids ~22-way bank conflicts on the
// transpose writes); k-loop reads are aligned b128. In-place (in==out) is safe: each block
// stages its full row-tile before writing.

template <int NOUT, bool RELU>
__global__ __launch_bounds__(192) void gemm96_kernel(const float* in,
    const float* __restrict__ W, const float* __restrict__ bias, float* out) {
  constexpr int NPAD = (NOUT == 96) ? 96 : 48;
  constexpr int TN = NPAD / 12;  // 8 or 4
  __shared__ float sZ[96][64];   // [k][node], quad-swizzled along node
  __shared__ float sW[96 * NPAD];
  __shared__ float sB[NPAD];

  int tid = threadIdx.x;
  int node0 = blockIdx.x * 64;

  // stage weights (padded cols = 0)
  for (int idx = tid; idx < 96 * NPAD; idx += 192) {
    int k = idx / NPAD, j = idx % NPAD;
    sW[idx] = (j < NOUT) ? W[k * NOUT + j] : 0.0f;
  }
  if (tid < NPAD) sB[tid] = (tid < NOUT) ? bias[tid] : 0.0f;

  // stage input tile, transposed, with XOR quad swizzle:
  // element (k,row) lives at sZ[k][(row&3) | ((((row>>2) ^ ((k>>2)&15))) << 2)]
  for (int idx = tid; idx < 64 * 24; idx += 192) {
    int row = idx / 24, c4 = idx % 24;  // c4: float4 index along k
    int node = node0 + row;
    float4 v = make_float4(0.f, 0.f, 0.f, 0.f);
    if (node < NODES) v = ((const float4*)(in + (size_t)node * FDIM))[c4];
    int pcol = (row & 3) | ((((row >> 2) ^ (c4 & 15))) << 2);
    sZ[4 * c4 + 0][pcol] = v.x;
    sZ[4 * c4 + 1][pcol] = v.y;
    sZ[4 * c4 + 2][pcol] = v.z;
    sZ[4 * c4 + 3][pcol] = v.w;
  }
  __syncthreads();

  int tx = tid & 15, ty = tid >> 4;  // tx: node quad, ty in 0..11: output group
  float acc[4][TN];
#pragma unroll
  for (int i = 0; i < 4; ++i)
#pragma unroll
    for (int j = 0; j < TN; ++j) acc[i][j] = sB[ty * TN + j];

#pragma unroll 4
  for (int k = 0; k < 96; ++k) {
    int pq = tx ^ ((k >> 2) & 15);
    float4 zv = *(const float4*)&sZ[k][pq * 4];
    float zr[4] = {zv.x, zv.y, zv.z, zv.w};
    float wr[TN];
#pragma unroll
    for (int j = 0; j < TN; j += 4) {
      float4 wv = *(const float4*)&sW[k * NPAD + ty * TN + j];
      wr[j] = wv.x; wr[j + 1] = wv.y; wr[j + 2] = wv.z; wr[j + 3] = wv.w;
    }
#pragma unroll
    for (int i = 0; i < 4; ++i)
#pragma unroll
      for (int j = 0; j < TN; ++j) acc[i][j] = fmaf(zr[i], wr[j], acc[i][j]);
  }

#pragma unroll
  for (int i = 0; i < 4; ++i) {
    int node = node0 + tx * 4 + i;
    if (node >= NODES) continue;
#pragma unroll
    for (int j = 0; j < TN; j += 4) {
      int j0 = ty * TN + j;
      if (j0 < NOUT) {
        float4 v = make_float4(acc[i][j], acc[i][j + 1], acc[i][j + 2], acc[i][j + 3]);
        if (RELU) {
          v.x = fmaxf(v.x, 0.f); v.y = fmaxf(v.y, 0.f);
          v.z = fmaxf(v.z, 0.f); v.w = fmaxf(v.w, 0.f);
        }
        *(float4*)&out[(size_t)node * NOUT + j0] = v;
      }
    }
  }
}

// ---------------- launch ----------------

extern "C" void kernel_launch(void* const* d_in, const int* in_sizes, int n_in,
                              void* d_out, int out_size, void* d_ws, size_t ws_size,
                              hipStream_t stream) {
  const float* x    = (const float*)d_in[0];
  const int*   ei   = (const int*)d_in[1];   // [2][E]: src row then dst row
  const float* W1a  = (const float*)d_in[2];
  const float* b1a  = (const float*)d_in[3];
  const float* W1b  = (const float*)d_in[4];
  const float* b1b  = (const float*)d_in[5];
  const float* W2a  = (const float*)d_in[6];
  const float* b2a  = (const float*)d_in[7];
  const float* W2b  = (const float*)d_in[8];
  const float* b2b  = (const float*)d_in[9];
  float* out = (float*)d_out;

  const int* src = ei;
  const int* dst = ei + EDGES;

  // workspace layout
  char* ws = (char*)d_ws;
  size_t off = 0;
  auto alloc = [&](size_t bytes) {
    size_t p = off;
    off = (off + bytes + 255) & ~(size_t)255;
    return p;
  };
  int* cnt     = (int*)(ws + alloc((size_t)NODES * 4));
  int* row_ptr = (int*)(ws + alloc((size_t)(NODES + 1) * 4));
  int* cursor  = (int*)(ws + alloc((size_t)NODES * 4));
  int* col     = (int*)(ws + alloc((size_t)EDGES * 4));
  float* bufA  = (float*)(ws + alloc((size_t)NODES * FDIM * 4));
  float* bufB  = (float*)(ws + alloc((size_t)NODES * FDIM * 4));

  // CSR build (per call; deterministic up to f32 sum order)
  zero_int_kernel<<<(NODES + 255) / 256, 256, 0, stream>>>(cnt, NODES);
  count_deg_kernel<<<(EDGES + 255) / 256, 256, 0, stream>>>(dst, cnt);
  scan_kernel<<<1, 1024, 0, stream>>>(cnt, row_ptr, cursor);
  fill_csr_kernel<<<(EDGES + 255) / 256, 256, 0, stream>>>(src, dst, cursor, col);

  const int AGG_GRID = (NODES * 32) / 256;       // 6250
  const int GEMM_GRID = (NODES + 63) / 64;       // 782

  // layer 1
  aggregate_kernel<<<AGG_GRID, 256, 0, stream>>>(x, row_ptr, col, bufA);
  gemm96_kernel<96, true><<<GEMM_GRID, 192, 0, stream>>>(bufA, W1a, b1a, bufA);
  gemm96_kernel<96, true><<<GEMM_GRID, 192, 0, stream>>>(bufA, W1b, b1b, bufB);  // h = relu(...)

  // layer 2
  aggregate_kernel<<<AGG_GRID, 256, 0, stream>>>(bufB, row_ptr, col, bufA);
  gemm96_kernel<96, true><<<GEMM_GRID, 192, 0, stream>>>(bufA, W2a, b2a, bufA);
  gemm96_kernel<40, false><<<GEMM_GRID, 192, 0, stream>>>(bufA, W2b, b2b, out);
}

// Round 2
// 321.689 us; speedup vs baseline: 1.3639x; 1.3639x over previous
//
#include <hip/hip_runtime.h>

#define NODES 50000
#define EDGES 800000
#define FDIM  96
#define NCLS  40

#define SCAN_BLOCKS 256  // 256 blocks x 256 threads = 65536 >= NODES, 1 node/thread

// ---------------- CSR build ----------------

__global__ void zero_int_kernel(int* __restrict__ p, int n) {
  int i = blockIdx.x * blockDim.x + threadIdx.x;
  if (i < n) p[i] = 0;
}

__global__ void count_deg_kernel(const int* __restrict__ dst, int* __restrict__ cnt) {
  int e = blockIdx.x * blockDim.x + threadIdx.x;
  if (e < EDGES) atomicAdd(&cnt[dst[e]], 1);
}

// stage 1: per-block sums of cnt
__global__ __launch_bounds__(256) void partial_kernel(const int* __restrict__ cnt,
                                                      int* __restrict__ partials) {
  __shared__ int sh[256];
  int t = threadIdx.x;
  int idx = blockIdx.x * 256 + t;
  int v = (idx < NODES) ? cnt[idx] : 0;
  sh[t] = v;
  __syncthreads();
#pragma unroll
  for (int d = 1; d < 256; d <<= 1) {
    int u = (t >= d) ? sh[t - d] : 0;
    __syncthreads();
    sh[t] += u;
    __syncthreads();
  }
  if (t == 255) partials[blockIdx.x] = sh[255];
}

// stage 2: exclusive scan of the 256 partials
__global__ __launch_bounds__(256) void scan_partials_kernel(int* __restrict__ partials,
                                                            int* __restrict__ poffs) {
  __shared__ int sh[256];
  int t = threadIdx.x;
  int v = partials[t];
  sh[t] = v;
  __syncthreads();
#pragma unroll
  for (int d = 1; d < 256; d <<= 1) {
    int u = (t >= d) ? sh[t - d] : 0;
    __syncthreads();
    sh[t] += u;
    __syncthreads();
  }
  poffs[t] = sh[t] - v;  // exclusive
}

// stage 3: within-block exclusive scan + block offset -> row_ptr, cursor
__global__ __launch_bounds__(256) void final_scan_kernel(const int* __restrict__ cnt,
                                                         const int* __restrict__ poffs,
                                                         int* __restrict__ row_ptr,
                                                         int* __restrict__ cursor) {
  __shared__ int sh[256];
  int t = threadIdx.x;
  int idx = blockIdx.x * 256 + t;
  int v = (idx < NODES) ? cnt[idx] : 0;
  sh[t] = v;
  __syncthreads();
#pragma unroll
  for (int d = 1; d < 256; d <<= 1) {
    int u = (t >= d) ? sh[t - d] : 0;
    __syncthreads();
    sh[t] += u;
    __syncthreads();
  }
  if (idx < NODES) {
    int excl = poffs[blockIdx.x] + sh[t] - v;
    row_ptr[idx] = excl;
    cursor[idx]  = excl;
  }
  if (idx == 0) row_ptr[NODES] = EDGES;  // every dst in [0,NODES) -> total = EDGES
}

__global__ void fill_csr_kernel(const int* __restrict__ src, const int* __restrict__ dst,
                                int* __restrict__ cursor, int* __restrict__ col) {
  int e = blockIdx.x * blockDim.x + threadIdx.x;
  if (e < EDGES) {
    int d = dst[e];
    int pos = atomicAdd(&cursor[d], 1);
    col[pos] = src[e];
  }
}

// ---------------- aggregation: z[i] = h[i] + sum_{j->i} h[j] ----------------
// 32 lanes per node, 3 features per lane (96 = 32*3), register accumulation.

__global__ __launch_bounds__(256) void aggregate_kernel(const float* __restrict__ hin,
    const int* __restrict__ row_ptr, const int* __restrict__ col, float* __restrict__ z) {
  int gt = blockIdx.x * blockDim.x + threadIdx.x;
  int node = gt >> 5;
  int l = gt & 31;
  if (node >= NODES) return;
  const float* self = hin + (size_t)node * FDIM;
  float a0 = self[l], a1 = self[l + 32], a2 = self[l + 64];
  int e1 = row_ptr[node + 1];
  for (int e = row_ptr[node]; e < e1; ++e) {
    const float* r = hin + (size_t)col[e] * FDIM;
    a0 += r[l];
    a1 += r[l + 32];
    a2 += r[l + 64];
  }
  float* zp = z + (size_t)node * FDIM;
  zp[l] = a0; zp[l + 32] = a1; zp[l + 64] = a2;
}

// ---------------- tiled f32 GEMM: out[n, j] = relu?(in[n,:] @ W[:, j] + b[j]) ----------------
// Block tile: 64 nodes x NOUT. 192 threads = 16 node-threads (TM=4) x 12 out-threads (TN=NPAD/12).
// z-tile staged transposed in LDS with XOR quad-swizzle (avoids ~22-way bank conflicts on the
// transpose writes); k-loop reads are aligned b128. In-place (in==out) is safe: each block
// stages its full row-tile before writing.

template <int NOUT, bool RELU>
__global__ __launch_bounds__(192) void gemm96_kernel(const float* in,
    const float* __restrict__ W, const float* __restrict__ bias, float* out) {
  constexpr int NPAD = (NOUT == 96) ? 96 : 48;
  constexpr int TN = NPAD / 12;  // 8 or 4
  __shared__ float sZ[96][64];   // [k][node], quad-swizzled along node
  __shared__ float sW[96 * NPAD];
  __shared__ float sB[NPAD];

  int tid = threadIdx.x;
  int node0 = blockIdx.x * 64;

  // stage weights (padded cols = 0)
  for (int idx = tid; idx < 96 * NPAD; idx += 192) {
    int k = idx / NPAD, j = idx % NPAD;
    sW[idx] = (j < NOUT) ? W[k * NOUT + j] : 0.0f;
  }
  if (tid < NPAD) sB[tid] = (tid < NOUT) ? bias[tid] : 0.0f;

  // stage input tile, transposed, with XOR quad swizzle:
  // element (k,row) lives at sZ[k][(row&3) | ((((row>>2) ^ ((k>>2)&15))) << 2)]
  for (int idx = tid; idx < 64 * 24; idx += 192) {
    int row = idx / 24, c4 = idx % 24;  // c4: float4 index along k
    int node = node0 + row;
    float4 v = make_float4(0.f, 0.f, 0.f, 0.f);
    if (node < NODES) v = ((const float4*)(in + (size_t)node * FDIM))[c4];
    int pcol = (row & 3) | ((((row >> 2) ^ (c4 & 15))) << 2);
    sZ[4 * c4 + 0][pcol] = v.x;
    sZ[4 * c4 + 1][pcol] = v.y;
    sZ[4 * c4 + 2][pcol] = v.z;
    sZ[4 * c4 + 3][pcol] = v.w;
  }
  __syncthreads();

  int tx = tid & 15, ty = tid >> 4;  // tx: node quad, ty in 0..11: output group
  float acc[4][TN];
#pragma unroll
  for (int i = 0; i < 4; ++i)
#pragma unroll
    for (int j = 0; j < TN; ++j) acc[i][j] = sB[ty * TN + j];

#pragma unroll 4
  for (int k = 0; k < 96; ++k) {
    int pq = tx ^ ((k >> 2) & 15);
    float4 zv = *(const float4*)&sZ[k][pq * 4];
    float zr[4] = {zv.x, zv.y, zv.z, zv.w};
    float wr[TN];
#pragma unroll
    for (int j = 0; j < TN; j += 4) {
      float4 wv = *(const float4*)&sW[k * NPAD + ty * TN + j];
      wr[j] = wv.x; wr[j + 1] = wv.y; wr[j + 2] = wv.z; wr[j + 3] = wv.w;
    }
#pragma unroll
    for (int i = 0; i < 4; ++i)
#pragma unroll
      for (int j = 0; j < TN; ++j) acc[i][j] = fmaf(zr[i], wr[j], acc[i][j]);
  }

#pragma unroll
  for (int i = 0; i < 4; ++i) {
    int node = node0 + tx * 4 + i;
    if (node >= NODES) continue;
#pragma unroll
    for (int j = 0; j < TN; j += 4) {
      int j0 = ty * TN + j;
      if (j0 < NOUT) {
        float4 v = make_float4(acc[i][j], acc[i][j + 1], acc[i][j + 2], acc[i][j + 3]);
        if (RELU) {
          v.x = fmaxf(v.x, 0.f); v.y = fmaxf(v.y, 0.f);
          v.z = fmaxf(v.z, 0.f); v.w = fmaxf(v.w, 0.f);
        }
        *(float4*)&out[(size_t)node * NOUT + j0] = v;
      }
    }
  }
}

// ---------------- launch ----------------

extern "C" void kernel_launch(void* const* d_in, const int* in_sizes, int n_in,
                              void* d_out, int out_size, void* d_ws, size_t ws_size,
                              hipStream_t stream) {
  const float* x    = (const float*)d_in[0];
  const int*   ei   = (const int*)d_in[1];   // [2][E]: src row then dst row
  const float* W1a  = (const float*)d_in[2];
  const float* b1a  = (const float*)d_in[3];
  const float* W1b  = (const float*)d_in[4];
  const float* b1b  = (const float*)d_in[5];
  const float* W2a  = (const float*)d_in[6];
  const float* b2a  = (const float*)d_in[7];
  const float* W2b  = (const float*)d_in[8];
  const float* b2b  = (const float*)d_in[9];
  float* out = (float*)d_out;

  const int* src = ei;
  const int* dst = ei + EDGES;

  // workspace layout
  char* ws = (char*)d_ws;
  size_t off = 0;
  auto alloc = [&](size_t bytes) {
    size_t p = off;
    off = (off + bytes + 255) & ~(size_t)255;
    return p;
  };
  int* cnt      = (int*)(ws + alloc((size_t)NODES * 4));
  int* row_ptr  = (int*)(ws + alloc((size_t)(NODES + 1) * 4));
  int* cursor   = (int*)(ws + alloc((size_t)NODES * 4));
  int* col      = (int*)(ws + alloc((size_t)EDGES * 4));
  int* partials = (int*)(ws + alloc((size_t)SCAN_BLOCKS * 4));
  int* poffs    = (int*)(ws + alloc((size_t)SCAN_BLOCKS * 4));
  float* bufA   = (float*)(ws + alloc((size_t)NODES * FDIM * 4));
  float* bufB   = (float*)(ws + alloc((size_t)NODES * FDIM * 4));

  // CSR build (per call; deterministic up to f32 sum order)
  zero_int_kernel<<<(NODES + 255) / 256, 256, 0, stream>>>(cnt, NODES);
  count_deg_kernel<<<(EDGES + 255) / 256, 256, 0, stream>>>(dst, cnt);
  partial_kernel<<<SCAN_BLOCKS, 256, 0, stream>>>(cnt, partials);
  scan_partials_kernel<<<1, 256, 0, stream>>>(partials, poffs);
  final_scan_kernel<<<SCAN_BLOCKS, 256, 0, stream>>>(cnt, poffs, row_ptr, cursor);
  fill_csr_kernel<<<(EDGES + 255) / 256, 256, 0, stream>>>(src, dst, cursor, col);

  const int AGG_GRID = (NODES * 32) / 256;       // 6250
  const int GEMM_GRID = (NODES + 63) / 64;       // 782

  // layer 1
  aggregate_kernel<<<AGG_GRID, 256, 0, stream>>>(x, row_ptr, col, bufA);
  gemm96_kernel<96, true><<<GEMM_GRID, 192, 0, stream>>>(bufA, W1a, b1a, bufA);
  gemm96_kernel<96, true><<<GEMM_GRID, 192, 0, stream>>>(bufA, W1b, b1b, bufB);  // h = relu(...)

  // layer 2
  aggregate_kernel<<<AGG_GRID, 256, 0, stream>>>(bufB, row_ptr, col, bufA);
  gemm96_kernel<96, true><<<GEMM_GRID, 192, 0, stream>>>(bufA, W2a, b2a, bufA);
  gemm96_kernel<40, false><<<GEMM_GRID, 192, 0, stream>>>(bufA, W2b, b2b, out);
}

// Round 3
// 236.438 us; speedup vs baseline: 1.8557x; 1.3606x over previous
//
#include <hip/hip_runtime.h>
#include <hip/hip_bf16.h>

#define NODES 50000
#define EDGES 800000
#define FDIM  96
#define NCLS  40

#define SCAN_BLOCKS 256  // 256 blocks x 256 threads = 65536 >= NODES, 1 node/thread

typedef __attribute__((ext_vector_type(8))) short s8v;    // 8 bf16 (4 VGPR) MFMA A/B frag
typedef __attribute__((ext_vector_type(4))) float f32x4;  // MFMA C/D frag

// ---------------- CSR build ----------------

__global__ void zero_int_kernel(int* __restrict__ p, int n) {
  int i = blockIdx.x * blockDim.x + threadIdx.x;
  if (i < n) p[i] = 0;
}

__global__ void count_deg_kernel(const int* __restrict__ dst, int* __restrict__ cnt) {
  int e = blockIdx.x * blockDim.x + threadIdx.x;
  if (e < EDGES) atomicAdd(&cnt[dst[e]], 1);
}

// stage 1: per-block sums of cnt
__global__ __launch_bounds__(256) void partial_kernel(const int* __restrict__ cnt,
                                                      int* __restrict__ partials) {
  __shared__ int sh[256];
  int t = threadIdx.x;
  int idx = blockIdx.x * 256 + t;
  int v = (idx < NODES) ? cnt[idx] : 0;
  sh[t] = v;
  __syncthreads();
#pragma unroll
  for (int d = 1; d < 256; d <<= 1) {
    int u = (t >= d) ? sh[t - d] : 0;
    __syncthreads();
    sh[t] += u;
    __syncthreads();
  }
  if (t == 255) partials[blockIdx.x] = sh[255];
}

// stage 2: exclusive scan of the 256 partials
__global__ __launch_bounds__(256) void scan_partials_kernel(int* __restrict__ partials,
                                                            int* __restrict__ poffs) {
  __shared__ int sh[256];
  int t = threadIdx.x;
  int v = partials[t];
  sh[t] = v;
  __syncthreads();
#pragma unroll
  for (int d = 1; d < 256; d <<= 1) {
    int u = (t >= d) ? sh[t - d] : 0;
    __syncthreads();
    sh[t] += u;
    __syncthreads();
  }
  poffs[t] = sh[t] - v;  // exclusive
}

// stage 3: within-block exclusive scan + block offset -> row_ptr, cursor
__global__ __launch_bounds__(256) void final_scan_kernel(const int* __restrict__ cnt,
                                                         const int* __restrict__ poffs,
                                                         int* __restrict__ row_ptr,
                                                         int* __restrict__ cursor) {
  __shared__ int sh[256];
  int t = threadIdx.x;
  int idx = blockIdx.x * 256 + t;
  int v = (idx < NODES) ? cnt[idx] : 0;
  sh[t] = v;
  __syncthreads();
#pragma unroll
  for (int d = 1; d < 256; d <<= 1) {
    int u = (t >= d) ? sh[t - d] : 0;
    __syncthreads();
    sh[t] += u;
    __syncthreads();
  }
  if (idx < NODES) {
    int excl = poffs[blockIdx.x] + sh[t] - v;
    row_ptr[idx] = excl;
    cursor[idx]  = excl;
  }
  if (idx == 0) row_ptr[NODES] = EDGES;  // every dst in [0,NODES) -> total = EDGES
}

__global__ void fill_csr_kernel(const int* __restrict__ src, const int* __restrict__ dst,
                                int* __restrict__ cursor, int* __restrict__ col) {
  int e = blockIdx.x * blockDim.x + threadIdx.x;
  if (e < EDGES) {
    int d = dst[e];
    int pos = atomicAdd(&cursor[d], 1);
    col[pos] = src[e];
  }
}

// ---------------- aggregation: z[i] = h[i] + sum_{j->i} h[j] ----------------
// 32 lanes per node, 3 features per lane. 4-way edge unroll: 12 independent
// row-loads in flight per iteration instead of one dependent chain.

__global__ __launch_bounds__(256) void aggregate_kernel(const float* __restrict__ hin,
    const int* __restrict__ row_ptr, const int* __restrict__ col, float* __restrict__ z) {
  int gt = blockIdx.x * blockDim.x + threadIdx.x;
  int node = gt >> 5;
  int l = gt & 31;
  if (node >= NODES) return;
  const float* self = hin + (size_t)node * FDIM;
  float a0 = self[l], a1 = self[l + 32], a2 = self[l + 64];
  int e = row_ptr[node];
  int e1 = row_ptr[node + 1];
  for (; e + 4 <= e1; e += 4) {
    int c0 = col[e], c1 = col[e + 1], c2 = col[e + 2], c3 = col[e + 3];
    const float* p0 = hin + (size_t)c0 * FDIM;
    const float* p1 = hin + (size_t)c1 * FDIM;
    const float* p2 = hin + (size_t)c2 * FDIM;
    const float* p3 = hin + (size_t)c3 * FDIM;
    float x00 = p0[l], x01 = p0[l + 32], x02 = p0[l + 64];
    float x10 = p1[l], x11 = p1[l + 32], x12 = p1[l + 64];
    float x20 = p2[l], x21 = p2[l + 32], x22 = p2[l + 64];
    float x30 = p3[l], x31 = p3[l + 32], x32 = p3[l + 64];
    a0 += (x00 + x10) + (x20 + x30);
    a1 += (x01 + x11) + (x21 + x31);
    a2 += (x02 + x12) + (x22 + x32);
  }
  for (; e < e1; ++e) {
    const float* r = hin + (size_t)col[e] * FDIM;
    a0 += r[l];
    a1 += r[l + 32];
    a2 += r[l + 64];
  }
  float* zp = z + (size_t)node * FDIM;
  zp[l] = a0; zp[l + 32] = a1; zp[l + 64] = a2;
}

// ---------------- weight prep: f32 [96][NOUT] -> bf16 [NOUT(pad48)][96] k-major ----------------
// wt layout: 4 slabs of 96*96 bf16. Slab m covers W{1a,1b,2a,2b}; slab 3 rows 40..47 zero-padded.

__global__ void prep_w_kernel(const float* __restrict__ W1a, const float* __restrict__ W1b,
                              const float* __restrict__ W2a, const float* __restrict__ W2b,
                              ushort* __restrict__ wt) {
  int id = blockIdx.x * blockDim.x + threadIdx.x;
  if (id >= 4 * 96 * 96) return;
  int m = id / (96 * 96);
  int r = (id % (96 * 96)) / 96;  // output col n
  int k = id % 96;
  float v = 0.0f;
  if (m == 0) v = W1a[k * 96 + r];
  else if (m == 1) v = W1b[k * 96 + r];
  else if (m == 2) v = W2a[k * 96 + r];
  else if (r < NCLS) v = W2b[k * NCLS + r];
  __hip_bfloat16 b = __float2bfloat16(v);
  wt[id] = *reinterpret_cast<ushort*>(&b);
}

// ---------------- MFMA GEMM: out[n,j] = relu?(in[n,:] @ W[:,j] + b[j]) ----------------
// 64-node tile x NOUT, 256 threads (4 waves x 16 rows). A,B staged bf16 in LDS with
// 256B row stride + XOR-16B swizzle (2-way max bank aliasing = free). f32 accum + f32 bias.
// Frag maps (m89-verified): A row=lane&15,k=(lane>>4)*8+e; B col=lane&15 same k;
// C col=lane&15,row=(lane>>4)*4+reg. In-place safe: full tile staged before stores.

template <int NOUT, bool RELU>
__global__ __launch_bounds__(256) void gemm_mfma_kernel(const float* in,
    const ushort* __restrict__ wt, const float* __restrict__ bias, float* out) {
  constexpr int NT = (NOUT == 96) ? 6 : 3;   // 16-col tiles
  constexpr int NRW = NT * 16;               // B rows staged (96 or 48)
  __shared__ ushort sA[64 * 128];            // [row][k] bf16, 256B stride
  __shared__ ushort sB[NRW * 128];           // [n][k] bf16, 256B stride
  __shared__ float sBias[NRW];

  int tid = threadIdx.x;
  int node0 = blockIdx.x * 64;

  // stage A: 64 rows x 96 f32 -> bf16, 8 elems/slot, 768 slots
  for (int s = tid; s < 64 * 12; s += 256) {
    int row = s / 12, k0 = (s % 12) * 8;
    int node = node0 + row;
    float4 v0 = make_float4(0.f, 0.f, 0.f, 0.f), v1 = v0;
    if (node < NODES) {
      const float4* p = (const float4*)(in + (size_t)node * FDIM + k0);
      v0 = p[0]; v1 = p[1];
    }
    ushort u[8];
    float f[8] = {v0.x, v0.y, v0.z, v0.w, v1.x, v1.y, v1.z, v1.w};
#pragma unroll
    for (int i = 0; i < 8; ++i) {
      __hip_bfloat16 b = __float2bfloat16(f[i]);
      u[i] = *reinterpret_cast<ushort*>(&b);
    }
    int uidx = (row * 128 + k0) ^ ((row & 7) << 3);
    *(uint4*)&sA[uidx] = *(const uint4*)u;
  }
  // stage B: NRW rows x 96 bf16 (already converted/transposed in wt)
  for (int s = tid; s < NRW * 12; s += 256) {
    int n = s / 12, k0 = (s % 12) * 8;
    uint4 v = *(const uint4*)(wt + n * 96 + k0);
    int uidx = (n * 128 + k0) ^ ((n & 7) << 3);
    *(uint4*)&sB[uidx] = v;
  }
  if (tid < NRW) sBias[tid] = (tid < NOUT) ? bias[tid] : 0.0f;
  __syncthreads();

  int lane = tid & 63;
  int wave = tid >> 6;
  int wrow0 = wave * 16;
  int arow = wrow0 + (lane & 15);
  int kgrp = (lane >> 4) * 8;

  // A frags for the 3 k-steps
  s8v a0 = *(const s8v*)&sA[(arow * 128 + 0  + kgrp) ^ ((arow & 7) << 3)];
  s8v a1 = *(const s8v*)&sA[(arow * 128 + 32 + kgrp) ^ ((arow & 7) << 3)];
  s8v a2 = *(const s8v*)&sA[(arow * 128 + 64 + kgrp) ^ ((arow & 7) << 3)];

#pragma unroll
  for (int nt = 0; nt < NT; ++nt) {
    int bcol = nt * 16 + (lane & 15);
    float bv = sBias[nt * 16 + (lane & 15)];
    f32x4 acc = {bv, bv, bv, bv};
    s8v b0 = *(const s8v*)&sB[(bcol * 128 + 0  + kgrp) ^ ((bcol & 7) << 3)];
    s8v b1 = *(const s8v*)&sB[(bcol * 128 + 32 + kgrp) ^ ((bcol & 7) << 3)];
    s8v b2 = *(const s8v*)&sB[(bcol * 128 + 64 + kgrp) ^ ((bcol & 7) << 3)];
    acc = __builtin_amdgcn_mfma_f32_16x16x32_bf16(a0, b0, acc, 0, 0, 0);
    acc = __builtin_amdgcn_mfma_f32_16x16x32_bf16(a1, b1, acc, 0, 0, 0);
    acc = __builtin_amdgcn_mfma_f32_16x16x32_bf16(a2, b2, acc, 0, 0, 0);
    int colg = nt * 16 + (lane & 15);
#pragma unroll
    for (int j = 0; j < 4; ++j) {
      int row = wrow0 + (lane >> 4) * 4 + j;
      int node = node0 + row;
      float v = acc[j];
      if (RELU) v = fmaxf(v, 0.0f);
      if (node < NODES && colg < NOUT) out[(size_t)node * NOUT + colg] = v;
    }
  }
}

// ---------------- launch ----------------

extern "C" void kernel_launch(void* const* d_in, const int* in_sizes, int n_in,
                              void* d_out, int out_size, void* d_ws, size_t ws_size,
                              hipStream_t stream) {
  const float* x    = (const float*)d_in[0];
  const int*   ei   = (const int*)d_in[1];   // [2][E]: src row then dst row
  const float* W1a  = (const float*)d_in[2];
  const float* b1a  = (const float*)d_in[3];
  const float* W1b  = (const float*)d_in[4];
  const float* b1b  = (const float*)d_in[5];
  const float* W2a  = (const float*)d_in[6];
  const float* b2a  = (const float*)d_in[7];
  const float* W2b  = (const float*)d_in[8];
  const float* b2b  = (const float*)d_in[9];
  float* out = (float*)d_out;

  const int* src = ei;
  const int* dst = ei + EDGES;

  // workspace layout
  char* ws = (char*)d_ws;
  size_t off = 0;
  auto alloc = [&](size_t bytes) {
    size_t p = off;
    off = (off + bytes + 255) & ~(size_t)255;
    return p;
  };
  int* cnt      = (int*)(ws + alloc((size_t)NODES * 4));
  int* row_ptr  = (int*)(ws + alloc((size_t)(NODES + 1) * 4));
  int* cursor   = (int*)(ws + alloc((size_t)NODES * 4));
  int* col      = (int*)(ws + alloc((size_t)EDGES * 4));
  int* partials = (int*)(ws + alloc((size_t)SCAN_BLOCKS * 4));
  int* poffs    = (int*)(ws + alloc((size_t)SCAN_BLOCKS * 4));
  ushort* wt    = (ushort*)(ws + alloc((size_t)4 * 96 * 96 * 2));
  float* bufA   = (float*)(ws + alloc((size_t)NODES * FDIM * 4));
  float* bufB   = (float*)(ws + alloc((size_t)NODES * FDIM * 4));

  // CSR build (per call; deterministic up to f32 sum order)
  zero_int_kernel<<<(NODES + 255) / 256, 256, 0, stream>>>(cnt, NODES);
  count_deg_kernel<<<(EDGES + 255) / 256, 256, 0, stream>>>(dst, cnt);
  partial_kernel<<<SCAN_BLOCKS, 256, 0, stream>>>(cnt, partials);
  scan_partials_kernel<<<1, 256, 0, stream>>>(partials, poffs);
  final_scan_kernel<<<SCAN_BLOCKS, 256, 0, stream>>>(cnt, poffs, row_ptr, cursor);
  fill_csr_kernel<<<(EDGES + 255) / 256, 256, 0, stream>>>(src, dst, cursor, col);
  prep_w_kernel<<<(4 * 96 * 96 + 255) / 256, 256, 0, stream>>>(W1a, W1b, W2a, W2b, wt);

  const int AGG_GRID = (NODES * 32) / 256;       // 6250
  const int GEMM_GRID = (NODES + 63) / 64;       // 782

  // layer 1
  aggregate_kernel<<<AGG_GRID, 256, 0, stream>>>(x, row_ptr, col, bufA);
  gemm_mfma_kernel<96, true><<<GEMM_GRID, 256, 0, stream>>>(bufA, wt + 0 * 9216, b1a, bufA);
  gemm_mfma_kernel<96, true><<<GEMM_GRID, 256, 0, stream>>>(bufA, wt + 1 * 9216, b1b, bufB);

  // layer 2
  aggregate_kernel<<<AGG_GRID, 256, 0, stream>>>(bufB, row_ptr, col, bufA);
  gemm_mfma_kernel<96, true><<<GEMM_GRID, 256, 0, stream>>>(bufA, wt + 2 * 9216, b2a, bufA);
  gemm_mfma_kernel<40, false><<<GEMM_GRID, 256, 0, stream>>>(bufA, wt + 3 * 9216, b2b, out);
}

// Round 4
// 165.493 us; speedup vs baseline: 2.6512x; 1.4287x over previous
//
#include <hip/hip_runtime.h>
#include <hip/hip_bf16.h>

#define NODES 50000
#define EDGES 800000
#define FDIM  96
#define NCLS  40

#define SCAN_BLOCKS 256  // 256 x 256 = 65536 >= NODES

typedef __attribute__((ext_vector_type(8))) short s8v;    // 8 bf16 MFMA A/B frag
typedef __attribute__((ext_vector_type(4))) float f32x4;  // MFMA C/D frag

__device__ __forceinline__ float b2f(ushort u) {
  unsigned int x = ((unsigned int)u) << 16;
  union { unsigned int i; float f; } c; c.i = x; return c.f;
}
__device__ __forceinline__ ushort f2b(float f) {
  __hip_bfloat16 b = __float2bfloat16(f);  // RNE
  return *reinterpret_cast<ushort*>(&b);
}

// ---------------- CSR build ----------------

__global__ void zero_int_kernel(int* __restrict__ p, int n) {
  int i = blockIdx.x * blockDim.x + threadIdx.x;
  if (i < n) p[i] = 0;
}

// single atomic pass: per-edge rank within its dst bucket (+ degree count).
// 4 edges/thread -> 4 independent atomic chains in flight.
__global__ __launch_bounds__(256) void rank_kernel(const int* __restrict__ dst,
                                                   int* __restrict__ cnt,
                                                   int* __restrict__ rank) {
  int base = blockIdx.x * 1024 + threadIdx.x;
#pragma unroll
  for (int i = 0; i < 4; ++i) {
    int e = base + i * 256;
    if (e < EDGES) {
      int d = dst[e];
      rank[e] = atomicAdd(&cnt[d], 1);
    }
  }
}

// stage 1: per-block sums of cnt
__global__ __launch_bounds__(256) void partial_kernel(const int* __restrict__ cnt,
                                                      int* __restrict__ partials) {
  __shared__ int sh[256];
  int t = threadIdx.x;
  int idx = blockIdx.x * 256 + t;
  int v = (idx < NODES) ? cnt[idx] : 0;
  sh[t] = v;
  __syncthreads();
#pragma unroll
  for (int d = 1; d < 256; d <<= 1) {
    int u = (t >= d) ? sh[t - d] : 0;
    __syncthreads();
    sh[t] += u;
    __syncthreads();
  }
  if (t == 255) partials[blockIdx.x] = sh[255];
}

// stage 2: exclusive scan of the 256 partials
__global__ __launch_bounds__(256) void scan_partials_kernel(int* __restrict__ partials,
                                                            int* __restrict__ poffs) {
  __shared__ int sh[256];
  int t = threadIdx.x;
  int v = partials[t];
  sh[t] = v;
  __syncthreads();
#pragma unroll
  for (int d = 1; d < 256; d <<= 1) {
    int u = (t >= d) ? sh[t - d] : 0;
    __syncthreads();
    sh[t] += u;
    __syncthreads();
  }
  poffs[t] = sh[t] - v;  // exclusive
}

// stage 3: within-block exclusive scan + block offset -> row_ptr
__global__ __launch_bounds__(256) void final_scan_kernel(const int* __restrict__ cnt,
                                                         const int* __restrict__ poffs,
                                                         int* __restrict__ row_ptr) {
  __shared__ int sh[256];
  int t = threadIdx.x;
  int idx = blockIdx.x * 256 + t;
  int v = (idx < NODES) ? cnt[idx] : 0;
  sh[t] = v;
  __syncthreads();
#pragma unroll
  for (int d = 1; d < 256; d <<= 1) {
    int u = (t >= d) ? sh[t - d] : 0;
    __syncthreads();
    sh[t] += u;
    __syncthreads();
  }
  if (idx < NODES) row_ptr[idx] = poffs[blockIdx.x] + sh[t] - v;
  if (idx == 0) row_ptr[NODES] = EDGES;
}

// no-atomic fill: pos = row_ptr[dst] + rank. Scatter write is fire-and-forget.
__global__ __launch_bounds__(256) void fill_csr_kernel(const int* __restrict__ src,
                                                       const int* __restrict__ dst,
                                                       const int* __restrict__ row_ptr,
                                                       const int* __restrict__ rank,
                                                       int* __restrict__ col) {
  int base = blockIdx.x * 1024 + threadIdx.x;
#pragma unroll
  for (int i = 0; i < 4; ++i) {
    int e = base + i * 256;
    if (e < EDGES) {
      int d = dst[e];
      col[row_ptr[d] + rank[e]] = src[e];
    }
  }
}

// ---------------- f32 -> bf16 feature conversion ----------------

__global__ void f2b_kernel(const float* __restrict__ in, ushort* __restrict__ out, int n4) {
  int i = blockIdx.x * blockDim.x + threadIdx.x;
  if (i < n4) {
    float4 v = ((const float4*)in)[i];
    ushort4 u;
    u.x = f2b(v.x); u.y = f2b(v.y); u.z = f2b(v.z); u.w = f2b(v.w);
    ((ushort4*)out)[i] = u;
  }
}

// ---------------- aggregation (bf16 in/out, f32 accum) ----------------
// 32 lanes/node, 3 features/lane; 4-way edge unroll (12 independent gathers in flight).

__global__ __launch_bounds__(256) void aggregate_kernel(const ushort* __restrict__ hin,
    const int* __restrict__ row_ptr, const int* __restrict__ col, ushort* __restrict__ z) {
  int gt = blockIdx.x * blockDim.x + threadIdx.x;
  int node = gt >> 5;
  int l = gt & 31;
  if (node >= NODES) return;
  const ushort* self = hin + (size_t)node * FDIM;
  float a0 = b2f(self[l]), a1 = b2f(self[l + 32]), a2 = b2f(self[l + 64]);
  int e = row_ptr[node];
  int e1 = row_ptr[node + 1];
  for (; e + 4 <= e1; e += 4) {
    int c0 = col[e], c1 = col[e + 1], c2 = col[e + 2], c3 = col[e + 3];
    const ushort* p0 = hin + (size_t)c0 * FDIM;
    const ushort* p1 = hin + (size_t)c1 * FDIM;
    const ushort* p2 = hin + (size_t)c2 * FDIM;
    const ushort* p3 = hin + (size_t)c3 * FDIM;
    float x00 = b2f(p0[l]), x01 = b2f(p0[l + 32]), x02 = b2f(p0[l + 64]);
    float x10 = b2f(p1[l]), x11 = b2f(p1[l + 32]), x12 = b2f(p1[l + 64]);
    float x20 = b2f(p2[l]), x21 = b2f(p2[l + 32]), x22 = b2f(p2[l + 64]);
    float x30 = b2f(p3[l]), x31 = b2f(p3[l + 32]), x32 = b2f(p3[l + 64]);
    a0 += (x00 + x10) + (x20 + x30);
    a1 += (x01 + x11) + (x21 + x31);
    a2 += (x02 + x12) + (x22 + x32);
  }
  for (; e < e1; ++e) {
    const ushort* r = hin + (size_t)col[e] * FDIM;
    a0 += b2f(r[l]);
    a1 += b2f(r[l + 32]);
    a2 += b2f(r[l + 64]);
  }
  ushort* zp = z + (size_t)node * FDIM;
  zp[l] = f2b(a0); zp[l + 32] = f2b(a1); zp[l + 64] = f2b(a2);
}

// ---------------- weight prep: f32 [96][NOUT] -> bf16 [96 rows][96] k-major ----------------

__global__ void prep_w_kernel(const float* __restrict__ W1a, const float* __restrict__ W1b,
                              const float* __restrict__ W2a, const float* __restrict__ W2b,
                              ushort* __restrict__ wt) {
  int id = blockIdx.x * blockDim.x + threadIdx.x;
  if (id >= 4 * 96 * 96) return;
  int m = id / (96 * 96);
  int r = (id % (96 * 96)) / 96;  // output col n
  int k = id % 96;
  float v = 0.0f;
  if (m == 0) v = W1a[k * 96 + r];
  else if (m == 1) v = W1b[k * 96 + r];
  else if (m == 2) v = W2a[k * 96 + r];
  else if (r < NCLS) v = W2b[k * NCLS + r];
  wt[id] = f2b(v);
}

// ---------------- LDS-free MFMA GEMM ----------------
// Each wave owns a 16-row tile; A/B fragments loaded directly from global
// (A rows streamed, wt 18KB L1-hot). Frag maps (m89-verified):
// A: row=lane&15, k=(lane>>4)*8+e (16B contiguous); B: col=lane&15, same k;
// C/D: col=lane&15, row=(lane>>4)*4+reg. No LDS, no syncthreads.

template <int NOUT, bool RELU, bool OUT_BF16>
__global__ __launch_bounds__(256) void gemm_mfma_kernel(const ushort* __restrict__ A,
    const ushort* __restrict__ wt, const float* __restrict__ bias, void* __restrict__ outv) {
  constexpr int NT = (NOUT == 96) ? 6 : 3;  // 16-col tiles
  int lane = threadIdx.x & 63;
  int wave = threadIdx.x >> 6;
  int row0 = (blockIdx.x * 4 + wave) * 16;
  int r = lane & 15;
  int kq = lane >> 4;  // 0..3

  int arow = row0 + r;
  if (arow >= NODES) arow = NODES - 1;  // clamp loads; stores guarded
  const ushort* ap = A + (size_t)arow * 96 + kq * 8;
  s8v a0 = *(const s8v*)(ap);
  s8v a1 = *(const s8v*)(ap + 32);
  s8v a2 = *(const s8v*)(ap + 64);

#pragma unroll
  for (int nt = 0; nt < NT; ++nt) {
    int colg = nt * 16 + r;
    const ushort* bp = wt + (size_t)colg * 96 + kq * 8;
    s8v b0 = *(const s8v*)(bp);
    s8v b1 = *(const s8v*)(bp + 32);
    s8v b2 = *(const s8v*)(bp + 64);
    float bv = (colg < NOUT) ? bias[colg] : 0.0f;
    f32x4 acc = {bv, bv, bv, bv};
    acc = __builtin_amdgcn_mfma_f32_16x16x32_bf16(a0, b0, acc, 0, 0, 0);
    acc = __builtin_amdgcn_mfma_f32_16x16x32_bf16(a1, b1, acc, 0, 0, 0);
    acc = __builtin_amdgcn_mfma_f32_16x16x32_bf16(a2, b2, acc, 0, 0, 0);
#pragma unroll
    for (int j = 0; j < 4; ++j) {
      int grow = row0 + kq * 4 + j;
      if (grow < NODES && colg < NOUT) {
        float v = acc[j];
        if (RELU) v = fmaxf(v, 0.0f);
        if (OUT_BF16)
          ((ushort*)outv)[(size_t)grow * NOUT + colg] = f2b(v);
        else
          ((float*)outv)[(size_t)grow * NOUT + colg] = v;
      }
    }
  }
}

// ---------------- launch ----------------

extern "C" void kernel_launch(void* const* d_in, const int* in_sizes, int n_in,
                              void* d_out, int out_size, void* d_ws, size_t ws_size,
                              hipStream_t stream) {
  const float* x    = (const float*)d_in[0];
  const int*   ei   = (const int*)d_in[1];   // [2][E]
  const float* W1a  = (const float*)d_in[2];
  const float* b1a  = (const float*)d_in[3];
  const float* W1b  = (const float*)d_in[4];
  const float* b1b  = (const float*)d_in[5];
  const float* W2a  = (const float*)d_in[6];
  const float* b2a  = (const float*)d_in[7];
  const float* W2b  = (const float*)d_in[8];
  const float* b2b  = (const float*)d_in[9];
  float* out = (float*)d_out;

  const int* src = ei;
  const int* dst = ei + EDGES;

  char* ws = (char*)d_ws;
  size_t off = 0;
  auto alloc = [&](size_t bytes) {
    size_t p = off;
    off = (off + bytes + 255) & ~(size_t)255;
    return p;
  };
  int* cnt      = (int*)(ws + alloc((size_t)NODES * 4));
  int* row_ptr  = (int*)(ws + alloc((size_t)(NODES + 1) * 4));
  int* rank     = (int*)(ws + alloc((size_t)EDGES * 4));
  int* col      = (int*)(ws + alloc((size_t)EDGES * 4));
  int* partials = (int*)(ws + alloc((size_t)SCAN_BLOCKS * 4));
  int* poffs    = (int*)(ws + alloc((size_t)SCAN_BLOCKS * 4));
  ushort* wt    = (ushort*)(ws + alloc((size_t)4 * 96 * 96 * 2));
  ushort* xb    = (ushort*)(ws + alloc((size_t)NODES * FDIM * 2));  // also reused as h
  ushort* B1    = (ushort*)(ws + alloc((size_t)NODES * FDIM * 2));
  ushort* B2    = (ushort*)(ws + alloc((size_t)NODES * FDIM * 2));

  const int EGRID = (EDGES + 1023) / 1024;       // 782 (4 edges/thread)
  const int AGG_GRID = (NODES * 32) / 256;       // 6250
  const int GEMM_GRID = (NODES + 63) / 64;       // 782

  // CSR build: one atomic pass + scan + no-atomic fill
  zero_int_kernel<<<(NODES + 255) / 256, 256, 0, stream>>>(cnt, NODES);
  rank_kernel<<<EGRID, 256, 0, stream>>>(dst, cnt, rank);
  partial_kernel<<<SCAN_BLOCKS, 256, 0, stream>>>(cnt, partials);
  scan_partials_kernel<<<1, 256, 0, stream>>>(partials, poffs);
  final_scan_kernel<<<SCAN_BLOCKS, 256, 0, stream>>>(cnt, poffs, row_ptr);
  fill_csr_kernel<<<EGRID, 256, 0, stream>>>(src, dst, row_ptr, rank, col);

  // feature prep
  prep_w_kernel<<<(4 * 96 * 96 + 255) / 256, 256, 0, stream>>>(W1a, W1b, W2a, W2b, wt);
  f2b_kernel<<<(NODES * FDIM / 4 + 255) / 256, 256, 0, stream>>>(x, xb, NODES * FDIM / 4);

  // layer 1: agg(xb)->B1; gemm->B2; gemm->xb (=h)
  aggregate_kernel<<<AGG_GRID, 256, 0, stream>>>(xb, row_ptr, col, B1);
  gemm_mfma_kernel<96, true, true><<<GEMM_GRID, 256, 0, stream>>>(B1, wt + 0 * 9216, b1a, B2);
  gemm_mfma_kernel<96, true, true><<<GEMM_GRID, 256, 0, stream>>>(B2, wt + 1 * 9216, b1b, xb);

  // layer 2: agg(h)->B1; gemm->B2; gemm->out (f32)
  aggregate_kernel<<<AGG_GRID, 256, 0, stream>>>(xb, row_ptr, col, B1);
  gemm_mfma_kernel<96, true, true><<<GEMM_GRID, 256, 0, stream>>>(B1, wt + 2 * 9216, b2a, B2);
  gemm_mfma_kernel<40, false, false><<<GEMM_GRID, 256, 0, stream>>>(B2, wt + 3 * 9216, b2b, out);
}

// Round 5
// 129.166 us; speedup vs baseline: 3.3969x; 1.2812x over previous
//
#include <hip/hip_runtime.h>
#include <hip/hip_bf16.h>

#define NODES 50000
#define EDGES 800000
#define FDIM  96
#define NCLS  40

// two-level counting sort geometry
#define NCHK 200                      // edge chunks (blocks)
#define CHKE 4000                     // EDGES / NCHK exactly
#define NB   196                      // coarse buckets of 256 nodes (dst>>8), 196*256=50176>=NODES
#define NCELL (NB * NCHK)             // 39200
#define SCAN_BLOCKS ((NCELL + 255) / 256)  // 154

typedef __attribute__((ext_vector_type(8))) short s8v;    // 8 bf16 MFMA A/B frag
typedef __attribute__((ext_vector_type(4))) float f32x4;  // MFMA C/D frag

__device__ __forceinline__ float b2f(ushort u) {
  unsigned int x = ((unsigned int)u) << 16;
  union { unsigned int i; float f; } c; c.i = x; return c.f;
}
__device__ __forceinline__ ushort f2b(float f) {
  __hip_bfloat16 b = __float2bfloat16(f);  // RNE
  return *reinterpret_cast<ushort*>(&b);
}

// ---------------- CSR build: two-level LDS counting sort (no global atomics) ----------------

// pass A: per-chunk histogram over coarse buckets
__global__ __launch_bounds__(256) void bin_count_kernel(const int* __restrict__ dst,
                                                        int* __restrict__ cellCnt) {
  __shared__ int hist[NB];
  int t = threadIdx.x;
  for (int i = t; i < NB; i += 256) hist[i] = 0;
  __syncthreads();
  int s = blockIdx.x * CHKE;
  for (int i = t; i < CHKE; i += 256) atomicAdd(&hist[dst[s + i] >> 8], 1);
  __syncthreads();
  for (int i = t; i < NB; i += 256) cellCnt[i * NCHK + blockIdx.x] = hist[i];
}

// generalized 3-stage exclusive scan over n ints
__global__ __launch_bounds__(256) void partial_kernel(const int* __restrict__ a, int n,
                                                      int* __restrict__ partials) {
  __shared__ int sh[256];
  int t = threadIdx.x;
  int idx = blockIdx.x * 256 + t;
  int v = (idx < n) ? a[idx] : 0;
  sh[t] = v;
  __syncthreads();
#pragma unroll
  for (int d = 1; d < 256; d <<= 1) {
    int u = (t >= d) ? sh[t - d] : 0;
    __syncthreads();
    sh[t] += u;
    __syncthreads();
  }
  if (t == 255) partials[blockIdx.x] = sh[255];
}

__global__ __launch_bounds__(256) void scan_partials_kernel(const int* __restrict__ partials,
                                                            int nb, int* __restrict__ poffs) {
  __shared__ int sh[256];
  int t = threadIdx.x;
  int v = (t < nb) ? partials[t] : 0;
  sh[t] = v;
  __syncthreads();
#pragma unroll
  for (int d = 1; d < 256; d <<= 1) {
    int u = (t >= d) ? sh[t - d] : 0;
    __syncthreads();
    sh[t] += u;
    __syncthreads();
  }
  if (t < nb) poffs[t] = sh[t] - v;  // exclusive
}

__global__ __launch_bounds__(256) void final_scan_kernel(const int* __restrict__ a, int n,
                                                         const int* __restrict__ poffs,
                                                         int* __restrict__ out) {
  __shared__ int sh[256];
  int t = threadIdx.x;
  int idx = blockIdx.x * 256 + t;
  int v = (idx < n) ? a[idx] : 0;
  sh[t] = v;
  __syncthreads();
#pragma unroll
  for (int d = 1; d < 256; d <<= 1) {
    int u = (t >= d) ? sh[t - d] : 0;
    __syncthreads();
    sh[t] += u;
    __syncthreads();
  }
  if (idx < n) out[idx] = poffs[blockIdx.x] + sh[t] - v;
}

// pass B: scatter (src,dst) records into per-(bucket,chunk) contiguous runs
__global__ __launch_bounds__(256) void bin_scatter_kernel(const int* __restrict__ src,
                                                          const int* __restrict__ dst,
                                                          const int* __restrict__ cellOff,
                                                          int2* __restrict__ ebuf) {
  __shared__ int cur[NB];
  int t = threadIdx.x;
  for (int i = t; i < NB; i += 256) cur[i] = cellOff[i * NCHK + blockIdx.x];
  __syncthreads();
  int s = blockIdx.x * CHKE;
  for (int i = t; i < CHKE; i += 256) {
    int d = dst[s + i];
    int pos = atomicAdd(&cur[d >> 8], 1);
    ebuf[pos] = make_int2(src[s + i], d);
  }
}

// pass C: per-bucket fine sort -> row_ptr + col (each block owns a private output window)
__global__ __launch_bounds__(256) void bucket_sort_kernel(const int2* __restrict__ ebuf,
                                                          const int* __restrict__ cellOff,
                                                          int* __restrict__ row_ptr,
                                                          int* __restrict__ col) {
  __shared__ int hist[256];
  __shared__ int sh[256];
  int b = blockIdx.x;
  int t = threadIdx.x;
  int s = cellOff[b * NCHK];
  int e = (b + 1 < NB) ? cellOff[(b + 1) * NCHK] : EDGES;
  hist[t] = 0;
  __syncthreads();
  for (int i = s + t; i < e; i += 256) atomicAdd(&hist[ebuf[i].y & 255], 1);
  __syncthreads();
  int v = hist[t];
  sh[t] = v;
  __syncthreads();
#pragma unroll
  for (int d = 1; d < 256; d <<= 1) {
    int u = (t >= d) ? sh[t - d] : 0;
    __syncthreads();
    sh[t] += u;
    __syncthreads();
  }
  int excl = sh[t] - v;
  int node = (b << 8) + t;
  if (node < NODES) row_ptr[node] = s + excl;
  if (node == NODES - 1) row_ptr[NODES] = EDGES;
  hist[t] = excl;  // reuse as cursor
  __syncthreads();
  for (int i = s + t; i < e; i += 256) {
    int2 ed = ebuf[i];
    int r = atomicAdd(&hist[ed.y & 255], 1);
    col[s + r] = ed.x;
  }
}

// ---------------- f32 -> bf16 feature conversion ----------------

__global__ void f2b_kernel(const float* __restrict__ in, ushort* __restrict__ out, int n4) {
  int i = blockIdx.x * blockDim.x + threadIdx.x;
  if (i < n4) {
    float4 v = ((const float4*)in)[i];
    ushort4 u;
    u.x = f2b(v.x); u.y = f2b(v.y); u.z = f2b(v.z); u.w = f2b(v.w);
    ((ushort4*)out)[i] = u;
  }
}

// ---------------- aggregation (bf16 in/out, f32 accum) ----------------
// 32 lanes/node, 3 features/lane; 8-way edge unroll (24 independent gathers in flight).

__global__ __launch_bounds__(256) void aggregate_kernel(const ushort* __restrict__ hin,
    const int* __restrict__ row_ptr, const int* __restrict__ col, ushort* __restrict__ z) {
  int gt = blockIdx.x * blockDim.x + threadIdx.x;
  int node = gt >> 5;
  int l = gt & 31;
  if (node >= NODES) return;
  const ushort* self = hin + (size_t)node * FDIM;
  float a0 = b2f(self[l]), a1 = b2f(self[l + 32]), a2 = b2f(self[l + 64]);
  int e = row_ptr[node];
  int e1 = row_ptr[node + 1];
  for (; e + 8 <= e1; e += 8) {
    const ushort* p[8];
#pragma unroll
    for (int q = 0; q < 8; ++q) p[q] = hin + (size_t)col[e + q] * FDIM;
    float s0 = 0.f, s1 = 0.f, s2 = 0.f;
#pragma unroll
    for (int q = 0; q < 8; ++q) {
      s0 += b2f(p[q][l]);
      s1 += b2f(p[q][l + 32]);
      s2 += b2f(p[q][l + 64]);
    }
    a0 += s0; a1 += s1; a2 += s2;
  }
  for (; e < e1; ++e) {
    const ushort* r = hin + (size_t)col[e] * FDIM;
    a0 += b2f(r[l]);
    a1 += b2f(r[l + 32]);
    a2 += b2f(r[l + 64]);
  }
  ushort* zp = z + (size_t)node * FDIM;
  zp[l] = f2b(a0); zp[l + 32] = f2b(a1); zp[l + 64] = f2b(a2);
}

// ---------------- weight prep: f32 [96][NOUT] -> bf16 [NOUT(pad)][96] k-major ----------------

__global__ void prep_w_kernel(const float* __restrict__ W1a, const float* __restrict__ W1b,
                              const float* __restrict__ W2a, const float* __restrict__ W2b,
                              ushort* __restrict__ wt) {
  int id = blockIdx.x * blockDim.x + threadIdx.x;
  if (id >= 4 * 96 * 96) return;
  int m = id / (96 * 96);
  int r = (id % (96 * 96)) / 96;  // output col n
  int k = id % 96;
  float v = 0.0f;
  if (m == 0) v = W1a[k * 96 + r];
  else if (m == 1) v = W1b[k * 96 + r];
  else if (m == 2) v = W2a[k * 96 + r];
  else if (r < NCLS) v = W2b[k * NCLS + r];
  wt[id] = f2b(v);
}

// ---------------- fused GIN MLP: out = (relu(z@Wa+ba))@Wb+bb, optional outer relu ----------------
// 64-row tile, 4 waves x 16 rows. Stage 1 LDS-free (A frags from global, Wa L1-hot);
// intermediate t staged bf16 in LDS [64][128] with XOR-16B swizzle; stage 2 reads
// A' frags from LDS, Wb from global. Frag maps (m89-verified):
// A row=lane&15, k=(lane>>4)*8+e; B col=lane&15 same k; C/D col=lane&15, row=(lane>>4)*4+j.

template <int NOUT2, bool RELU2, bool OUT_BF16>
__global__ __launch_bounds__(256) void gin_mlp_kernel(const ushort* __restrict__ A,
    const ushort* __restrict__ wtA, const float* __restrict__ biasA,
    const ushort* __restrict__ wtB, const float* __restrict__ biasB, void* __restrict__ outv) {
  constexpr int NT2 = (NOUT2 == 96) ? 6 : 3;
  __shared__ ushort sT[64 * 128];

  int lane = threadIdx.x & 63;
  int wave = threadIdx.x >> 6;
  int wrow0 = wave * 16;
  int node0 = blockIdx.x * 64;
  int r = lane & 15;
  int kq = lane >> 4;  // 0..3

  // stage 1: t = relu(z @ Wa + ba), 16 rows per wave
  int arow = node0 + wrow0 + r;
  if (arow >= NODES) arow = NODES - 1;  // clamp loads; stores guarded
  const ushort* ap = A + (size_t)arow * 96 + kq * 8;
  s8v a0 = *(const s8v*)(ap);
  s8v a1 = *(const s8v*)(ap + 32);
  s8v a2 = *(const s8v*)(ap + 64);

#pragma unroll
  for (int nt = 0; nt < 6; ++nt) {
    int colg = nt * 16 + r;
    const ushort* bp = wtA + (size_t)colg * 96 + kq * 8;
    s8v b0 = *(const s8v*)(bp);
    s8v b1 = *(const s8v*)(bp + 32);
    s8v b2 = *(const s8v*)(bp + 64);
    float bv = biasA[colg];
    f32x4 acc = {bv, bv, bv, bv};
    acc = __builtin_amdgcn_mfma_f32_16x16x32_bf16(a0, b0, acc, 0, 0, 0);
    acc = __builtin_amdgcn_mfma_f32_16x16x32_bf16(a1, b1, acc, 0, 0, 0);
    acc = __builtin_amdgcn_mfma_f32_16x16x32_bf16(a2, b2, acc, 0, 0, 0);
#pragma unroll
    for (int j = 0; j < 4; ++j) {
      int trow = wrow0 + kq * 4 + j;
      float v = fmaxf(acc[j], 0.0f);  // GIN MLP inner relu
      sT[(trow * 128 + colg) ^ ((trow & 7) << 3)] = f2b(v);
    }
  }
  __syncthreads();

  // stage 2: out = t @ Wb + bb
  int trow = wrow0 + r;
  int sbase = trow * 128;
  int swz = (trow & 7) << 3;
  s8v c0 = *(const s8v*)&sT[sbase + ((kq * 8 + 0)  ^ swz)];
  s8v c1 = *(const s8v*)&sT[sbase + ((kq * 8 + 32) ^ swz)];
  s8v c2 = *(const s8v*)&sT[sbase + ((kq * 8 + 64) ^ swz)];

#pragma unroll
  for (int nt = 0; nt < NT2; ++nt) {
    int colg = nt * 16 + r;
    const ushort* bp = wtB + (size_t)colg * 96 + kq * 8;
    s8v b0 = *(const s8v*)(bp);
    s8v b1 = *(const s8v*)(bp + 32);
    s8v b2 = *(const s8v*)(bp + 64);
    float bv = (colg < NOUT2) ? biasB[colg] : 0.0f;
    f32x4 acc = {bv, bv, bv, bv};
    acc = __builtin_amdgcn_mfma_f32_16x16x32_bf16(c0, b0, acc, 0, 0, 0);
    acc = __builtin_amdgcn_mfma_f32_16x16x32_bf16(c1, b1, acc, 0, 0, 0);
    acc = __builtin_amdgcn_mfma_f32_16x16x32_bf16(c2, b2, acc, 0, 0, 0);
#pragma unroll
    for (int j = 0; j < 4; ++j) {
      int grow = node0 + wrow0 + kq * 4 + j;
      if (grow < NODES && colg < NOUT2) {
        float v = acc[j];
        if (RELU2) v = fmaxf(v, 0.0f);
        if (OUT_BF16)
          ((ushort*)outv)[(size_t)grow * NOUT2 + colg] = f2b(v);
        else
          ((float*)outv)[(size_t)grow * NOUT2 + colg] = v;
      }
    }
  }
}

// ---------------- launch ----------------

extern "C" void kernel_launch(void* const* d_in, const int* in_sizes, int n_in,
                              void* d_out, int out_size, void* d_ws, size_t ws_size,
                              hipStream_t stream) {
  const float* x    = (const float*)d_in[0];
  const int*   ei   = (const int*)d_in[1];   // [2][E]
  const float* W1a  = (const float*)d_in[2];
  const float* b1a  = (const float*)d_in[3];
  const float* W1b  = (const float*)d_in[4];
  const float* b1b  = (const float*)d_in[5];
  const float* W2a  = (const float*)d_in[6];
  const float* b2a  = (const float*)d_in[7];
  const float* W2b  = (const float*)d_in[8];
  const float* b2b  = (const float*)d_in[9];
  float* out = (float*)d_out;

  const int* src = ei;
  const int* dst = ei + EDGES;

  char* ws = (char*)d_ws;
  size_t off = 0;
  auto alloc = [&](size_t bytes) {
    size_t p = off;
    off = (off + bytes + 255) & ~(size_t)255;
    return p;
  };
  int*  cellCnt  = (int*)(ws + alloc((size_t)NCELL * 4));
  int*  cellOff  = (int*)(ws + alloc((size_t)NCELL * 4));
  int*  partials = (int*)(ws + alloc((size_t)SCAN_BLOCKS * 4));
  int*  poffs    = (int*)(ws + alloc((size_t)SCAN_BLOCKS * 4));
  int*  row_ptr  = (int*)(ws + alloc((size_t)(NODES + 1) * 4));
  int2* ebuf     = (int2*)(ws + alloc((size_t)EDGES * 8));
  int*  col      = (int*)(ws + alloc((size_t)EDGES * 4));
  ushort* wt     = (ushort*)(ws + alloc((size_t)4 * 96 * 96 * 2));
  ushort* xb     = (ushort*)(ws + alloc((size_t)NODES * FDIM * 2));
  ushort* B1     = (ushort*)(ws + alloc((size_t)NODES * FDIM * 2));
  ushort* B2     = (ushort*)(ws + alloc((size_t)NODES * FDIM * 2));

  const int AGG_GRID  = (NODES * 32) / 256;   // 6250
  const int GEMM_GRID = (NODES + 63) / 64;    // 782

  // CSR build: two-level LDS counting sort
  bin_count_kernel<<<NCHK, 256, 0, stream>>>(dst, cellCnt);
  partial_kernel<<<SCAN_BLOCKS, 256, 0, stream>>>(cellCnt, NCELL, partials);
  scan_partials_kernel<<<1, 256, 0, stream>>>(partials, SCAN_BLOCKS, poffs);
  final_scan_kernel<<<SCAN_BLOCKS, 256, 0, stream>>>(cellCnt, NCELL, poffs, cellOff);
  bin_scatter_kernel<<<NCHK, 256, 0, stream>>>(src, dst, cellOff, ebuf);
  bucket_sort_kernel<<<NB, 256, 0, stream>>>(ebuf, cellOff, row_ptr, col);

  // feature / weight prep
  prep_w_kernel<<<(4 * 96 * 96 + 255) / 256, 256, 0, stream>>>(W1a, W1b, W2a, W2b, wt);
  f2b_kernel<<<(NODES * FDIM / 4 + 255) / 256, 256, 0, stream>>>(x, xb, NODES * FDIM / 4);

  // layer 1: agg(xb)->B1; fused MLP -> B2 (= relu(h))
  aggregate_kernel<<<AGG_GRID, 256, 0, stream>>>(xb, row_ptr, col, B1);
  gin_mlp_kernel<96, true, true><<<GEMM_GRID, 256, 0, stream>>>(
      B1, wt + 0 * 9216, b1a, wt + 1 * 9216, b1b, B2);

  // layer 2: agg(B2)->B1; fused MLP -> out (f32)
  aggregate_kernel<<<AGG_GRID, 256, 0, stream>>>(B2, row_ptr, col, B1);
  gin_mlp_kernel<40, false, false><<<GEMM_GRID, 256, 0, stream>>>(
      B1, wt + 2 * 9216, b2a, wt + 3 * 9216, b2b, out);
}